// Round 1
// baseline (1275.005 us; speedup 1.0000x reference)
//
#include <hip/hip_runtime.h>

typedef __attribute__((ext_vector_type(8))) __bf16 bf16x8;
typedef __attribute__((ext_vector_type(4))) __bf16 bf16x4;
typedef __attribute__((ext_vector_type(4))) float f32x4;

#define LL 2048
#define DD 2048
#define HH 16
#define HDIM 128

// ---------------- fp32 -> bf16 conversion ----------------
__global__ void cvt_f32_bf16(const float* __restrict__ src, __bf16* __restrict__ dst, int n4)
{
    int i = blockIdx.x * blockDim.x + threadIdx.x;
    if (i < n4) {
        float4 v = *(const float4*)(src + (size_t)i * 4);
        bf16x4 o = { (__bf16)v.x, (__bf16)v.y, (__bf16)v.z, (__bf16)v.w };
        *(bf16x4*)(dst + (size_t)i * 4) = o;
    }
}

// ---------------- bf16 GEMM: C = A(MxK) @ W(NxK)^T + bias ----------------
// 128x128 tile, BK=64, 4 waves (2x2), 16x16x32 MFMA.
// C/D layout (verified): col = lane&15, row = (lane>>4)*4 + reg.
template<bool OUT_BF16>
__global__ __launch_bounds__(256)
void gemm_bt(const __bf16* __restrict__ A, const __bf16* __restrict__ W,
             const float* __restrict__ bias, void* __restrict__ Cout,
             int M, int N, int K)
{
    __shared__ __bf16 As[128][72];   // +8 bf16 pad -> row stride 144B (kills bank conflict)
    __shared__ __bf16 Bs[128][72];
    const int tid  = threadIdx.x;
    const int m0   = blockIdx.y * 128;
    const int n0   = blockIdx.x * 128;
    const int wave = tid >> 6;
    const int lane = tid & 63;
    const int wr   = (wave >> 1) * 64;
    const int wc   = (wave & 1) * 64;
    const int lr   = lane & 15;
    const int lk   = (lane >> 4) * 8;
    const int srow = tid >> 3;          // 0..31
    const int scol = (tid & 7) * 8;     // 0..56

    f32x4 acc[4][4] = {};

    for (int k0 = 0; k0 < K; k0 += 64) {
        #pragma unroll
        for (int g = 0; g < 4; ++g) {
            const int r = srow + g * 32;
            *(int4*)(&As[r][scol]) = *(const int4*)(A + (size_t)(m0 + r) * K + k0 + scol);
            *(int4*)(&Bs[r][scol]) = *(const int4*)(W + (size_t)(n0 + r) * K + k0 + scol);
        }
        __syncthreads();
        #pragma unroll
        for (int ks = 0; ks < 2; ++ks) {
            bf16x8 af[4], bfr[4];
            #pragma unroll
            for (int m = 0; m < 4; ++m)
                af[m] = *(const bf16x8*)(&As[wr + m * 16 + lr][ks * 32 + lk]);
            #pragma unroll
            for (int n = 0; n < 4; ++n)
                bfr[n] = *(const bf16x8*)(&Bs[wc + n * 16 + lr][ks * 32 + lk]);
            #pragma unroll
            for (int m = 0; m < 4; ++m)
                #pragma unroll
                for (int n = 0; n < 4; ++n)
                    acc[m][n] = __builtin_amdgcn_mfma_f32_16x16x32_bf16(af[m], bfr[n], acc[m][n], 0, 0, 0);
        }
        __syncthreads();
    }

    const int orow = (lane >> 4) * 4;
    #pragma unroll
    for (int n = 0; n < 4; ++n) {
        const int col = n0 + wc + n * 16 + lr;
        const float bv = bias[col];
        #pragma unroll
        for (int m = 0; m < 4; ++m) {
            #pragma unroll
            for (int r = 0; r < 4; ++r) {
                const int row = m0 + wr + m * 16 + orow + r;
                const float v = acc[m][n][r] + bv;
                if (OUT_BF16) ((__bf16*)Cout)[(size_t)row * N + col] = (__bf16)v;
                else          ((float*)Cout)[(size_t)row * N + col]  = v;
            }
        }
    }
}

// ---------------- RoPE (in-place on bf16 q/k, layout (B,L,H*HD)) ----------------
__global__ void rope_k(__bf16* __restrict__ q, __bf16* __restrict__ k, const float* __restrict__ fc)
{
    __bf16* t = blockIdx.y ? k : q;
    const size_t e0 = ((size_t)blockIdx.x * blockDim.x + threadIdx.x) * 8;  // 4 pairs
    const int row = (int)(e0 >> 11);          // b*L + l
    const int l   = row & (LL - 1);
    const int din = (int)(e0 & (DD - 1));
    const int j0  = (din & (HDIM - 1)) >> 1;  // pair index within head (multiple of 4)
    bf16x8 v = *(bf16x8*)(t + e0);
    float4 c01 = *(const float4*)(fc + ((size_t)l * 64 + j0) * 2);
    float4 c23 = *(const float4*)(fc + ((size_t)l * 64 + j0 + 2) * 2);
    float cr[4] = { c01.x, c01.z, c23.x, c23.z };
    float ci[4] = { c01.y, c01.w, c23.y, c23.w };
    #pragma unroll
    for (int p = 0; p < 4; ++p) {
        float a = (float)v[2 * p], b = (float)v[2 * p + 1];
        v[2 * p]     = (__bf16)(a * cr[p] - b * ci[p]);
        v[2 * p + 1] = (__bf16)(a * ci[p] + b * cr[p]);
    }
    *(bf16x8*)(t + e0) = v;
}

// ---------------- latent projections: (b,h,l,:) 128 -> 32 ----------------
__global__ __launch_bounds__(256)
void latproj(const __bf16* __restrict__ qb, const __bf16* __restrict__ kb, const __bf16* __restrict__ vb,
             const float* __restrict__ Wq, const float* __restrict__ bq,
             const float* __restrict__ Wk, const float* __restrict__ bk,
             const float* __restrict__ Wv, const float* __restrict__ bv,
             float* __restrict__ qc, float* __restrict__ kc, float* __restrict__ vc)
{
    const int which = blockIdx.y;
    const __bf16* in = which == 0 ? qb : which == 1 ? kb : vb;
    const float*  W  = which == 0 ? Wq : which == 1 ? Wk : Wv;
    const float*  bs = which == 0 ? bq : which == 1 ? bk : bv;
    float*        out = which == 0 ? qc : which == 1 ? kc : vc;

    __shared__ float Ws[32][129];           // stride 129: conflict-free column reads
    for (int i = threadIdx.x; i < 32 * 128; i += 256)
        Ws[i >> 7][i & 127] = W[i];
    __syncthreads();

    const int o = threadIdx.x & 31;
    const int t = threadIdx.x >> 5;
    const size_t g = (size_t)blockIdx.x * 8 + t;   // (b*H + h)*L + l
    const int l  = (int)(g & (LL - 1));
    const int bh = (int)(g >> 11);
    const int h  = bh & (HH - 1);
    const int b  = bh >> 4;
    const __bf16* row = in + ((size_t)(b * LL + l) * DD + h * HDIM);
    float s = bs[o];
    #pragma unroll
    for (int d8 = 0; d8 < 16; ++d8) {
        bf16x8 rv = *(const bf16x8*)(row + d8 * 8);
        #pragma unroll
        for (int j = 0; j < 8; ++j)
            s += (float)rv[j] * Ws[o][d8 * 8 + j];
    }
    out[g * 32 + o] = s;
}

// ---------------- causal flash attention over LAT=32 ----------------
// 1 query row per thread, 64-row K/V tiles in LDS (broadcast reads), online softmax.
__global__ __launch_bounds__(64)
void attn_k(const float* __restrict__ qc, const float* __restrict__ kc, const float* __restrict__ vc,
            float* __restrict__ ao)
{
    __shared__ float Ks[64][36];
    __shared__ float Vs[64][36];
    const int tid = threadIdx.x;
    const int bh  = blockIdx.x >> 5;
    const int qt  = blockIdx.x & 31;
    const int i   = qt * 64 + tid;
    const size_t base = (size_t)bh * LL * 32;
    const float scale = 0.1767766952966369f;   // 1/sqrt(32)

    float q[32];
    #pragma unroll
    for (int c4 = 0; c4 < 8; ++c4) {
        float4 v = *(const float4*)(qc + base + (size_t)i * 32 + c4 * 4);
        q[c4 * 4 + 0] = v.x; q[c4 * 4 + 1] = v.y; q[c4 * 4 + 2] = v.z; q[c4 * 4 + 3] = v.w;
    }
    float m = -1e30f, lsum = 0.f;
    float o[32] = {};

    for (int t = 0; t <= qt; ++t) {
        const float* krow = kc + base + (size_t)(t * 64 + tid) * 32;
        const float* vrow = vc + base + (size_t)(t * 64 + tid) * 32;
        #pragma unroll
        for (int c4 = 0; c4 < 8; ++c4) {
            *(float4*)(&Ks[tid][c4 * 4]) = *(const float4*)(krow + c4 * 4);
            *(float4*)(&Vs[tid][c4 * 4]) = *(const float4*)(vrow + c4 * 4);
        }
        __syncthreads();
        const bool diag = (t == qt);
        #pragma unroll 1
        for (int ch = 0; ch < 4; ++ch) {
            float s[16];
            #pragma unroll
            for (int r = 0; r < 16; ++r) {
                const int rr = ch * 16 + r;
                float a = 0.f;
                #pragma unroll
                for (int c = 0; c < 32; ++c) a += q[c] * Ks[rr][c];
                s[r] = (diag && rr > tid) ? -1e30f : a * scale;
            }
            float tm = s[0];
            #pragma unroll
            for (int r = 1; r < 16; ++r) tm = fmaxf(tm, s[r]);
            const float nm = fmaxf(m, tm);
            const float f = __expf(m - nm);
            lsum *= f;
            #pragma unroll
            for (int c = 0; c < 32; ++c) o[c] *= f;
            m = nm;
            #pragma unroll
            for (int r = 0; r < 16; ++r) {
                const float p = __expf(s[r] - m);
                lsum += p;
                const int rr = ch * 16 + r;
                #pragma unroll
                for (int c = 0; c < 32; ++c) o[c] += p * Vs[rr][c];
            }
        }
        __syncthreads();
    }
    const float inv = 1.f / lsum;
    #pragma unroll
    for (int c = 0; c < 32; ++c)
        ao[base + (size_t)i * 32 + c] = o[c] * inv;
}

// ---------------- decode latent 32 -> 128, write (B,L,D) bf16 ----------------
__global__ __launch_bounds__(256)
void wd_k(const float* __restrict__ ao, const float* __restrict__ Wd, const float* __restrict__ bd,
          __bf16* __restrict__ out)
{
    __shared__ float Ws[128][33];
    for (int i = threadIdx.x; i < 128 * 32; i += 256)
        Ws[i >> 5][i & 31] = Wd[i];
    __syncthreads();
    const int hd = threadIdx.x & 127;
    const int t  = threadIdx.x >> 7;
    const size_t g = (size_t)blockIdx.x * 2 + t;   // (b*H + h)*L + l
    const int l  = (int)(g & (LL - 1));
    const int bh = (int)(g >> 11);
    const int h  = bh & (HH - 1);
    const int b  = bh >> 4;
    const float* arow = ao + g * 32;
    float s = bd[hd];
    #pragma unroll
    for (int c4 = 0; c4 < 8; ++c4) {
        float4 av = *(const float4*)(arow + c4 * 4);
        s += av.x * Ws[hd][c4 * 4 + 0] + av.y * Ws[hd][c4 * 4 + 1]
           + av.z * Ws[hd][c4 * 4 + 2] + av.w * Ws[hd][c4 * 4 + 3];
    }
    out[(size_t)(b * LL + l) * DD + h * HDIM + hd] = (__bf16)s;
}

extern "C" void kernel_launch(void* const* d_in, const int* in_sizes, int n_in,
                              void* d_out, int out_size, void* d_ws, size_t ws_size,
                              hipStream_t stream)
{
    const float* x   = (const float*)d_in[0];
    const float* fc  = (const float*)d_in[1];
    const float* Wq  = (const float*)d_in[2];
    const float* bq  = (const float*)d_in[3];
    const float* Wk  = (const float*)d_in[4];
    const float* bk  = (const float*)d_in[5];
    const float* Wv  = (const float*)d_in[6];
    const float* bv  = (const float*)d_in[7];
    const float* Wqc = (const float*)d_in[8];
    const float* bqc = (const float*)d_in[9];
    const float* Wkc = (const float*)d_in[10];
    const float* bkc = (const float*)d_in[11];
    const float* Wvc = (const float*)d_in[12];
    const float* bvc = (const float*)d_in[13];
    const float* Wd  = (const float*)d_in[14];
    const float* bd  = (const float*)d_in[15];
    const float* Wo  = (const float*)d_in[16];
    const float* bo  = (const float*)d_in[17];
    float* out = (float*)d_out;

    // workspace layout (151 MB total)
    char* w = (char*)d_ws;
    __bf16* xb  = (__bf16*)w; w += (size_t)4096 * 2048 * 2;
    __bf16* Wqb = (__bf16*)w; w += (size_t)2048 * 2048 * 2;
    __bf16* Wkb = (__bf16*)w; w += (size_t)2048 * 2048 * 2;
    __bf16* Wvb = (__bf16*)w; w += (size_t)2048 * 2048 * 2;
    __bf16* Wob = (__bf16*)w; w += (size_t)2048 * 2048 * 2;
    __bf16* qb  = (__bf16*)w; w += (size_t)4096 * 2048 * 2;
    __bf16* kb  = (__bf16*)w; w += (size_t)4096 * 2048 * 2;
    __bf16* vb  = (__bf16*)w; w += (size_t)4096 * 2048 * 2;
    float* qcb  = (float*)w;  w += (size_t)65536 * 32 * 4;
    float* kcb  = (float*)w;  w += (size_t)65536 * 32 * 4;
    float* vcb  = (float*)w;  w += (size_t)65536 * 32 * 4;
    float* aob  = (float*)w;  w += (size_t)65536 * 32 * 4;
    __bf16* adb = (__bf16*)w; w += (size_t)4096 * 2048 * 2;

    if (ws_size < (size_t)150994944) return;  // fail loudly (zero output) rather than corrupt

    cvt_f32_bf16<<<8192, 256, 0, stream>>>(x,  xb,  2097152);
    cvt_f32_bf16<<<4096, 256, 0, stream>>>(Wq, Wqb, 1048576);
    cvt_f32_bf16<<<4096, 256, 0, stream>>>(Wk, Wkb, 1048576);
    cvt_f32_bf16<<<4096, 256, 0, stream>>>(Wv, Wvb, 1048576);
    cvt_f32_bf16<<<4096, 256, 0, stream>>>(Wo, Wob, 1048576);

    dim3 ggrid(16, 32);
    gemm_bt<true><<<ggrid, 256, 0, stream>>>(xb, Wqb, bq, qb, 4096, 2048, 2048);
    gemm_bt<true><<<ggrid, 256, 0, stream>>>(xb, Wkb, bk, kb, 4096, 2048, 2048);
    gemm_bt<true><<<ggrid, 256, 0, stream>>>(xb, Wvb, bv, vb, 4096, 2048, 2048);

    rope_k<<<dim3(4096, 2), 256, 0, stream>>>(qb, kb, fc);

    latproj<<<dim3(8192, 3), 256, 0, stream>>>(qb, kb, vb, Wqc, bqc, Wkc, bkc, Wvc, bvc,
                                               qcb, kcb, vcb);

    attn_k<<<1024, 64, 0, stream>>>(qcb, kcb, vcb, aob);

    wd_k<<<32768, 256, 0, stream>>>(aob, Wd, bd, adb);

    gemm_bt<false><<<ggrid, 256, 0, stream>>>(adb, Wob, bo, out, 4096, 2048, 2048);
}

// Round 2
// 770.018 us; speedup vs baseline: 1.6558x; 1.6558x over previous
//
#include <hip/hip_runtime.h>

typedef __attribute__((ext_vector_type(8))) __bf16 bf16x8;
typedef __attribute__((ext_vector_type(4))) __bf16 bf16x4;
typedef __attribute__((ext_vector_type(4))) float f32x4;

#define LL 2048
#define DD 2048
#define HH 16
#define HDIM 128
#define CHUNK 512

// ---------------- fp32 -> bf16 conversion ----------------
__global__ void cvt_f32_bf16(const float* __restrict__ src, __bf16* __restrict__ dst, int n4)
{
    int i = blockIdx.x * blockDim.x + threadIdx.x;
    if (i < n4) {
        float4 v = *(const float4*)(src + (size_t)i * 4);
        bf16x4 o = { (__bf16)v.x, (__bf16)v.y, (__bf16)v.z, (__bf16)v.w };
        *(bf16x4*)(dst + (size_t)i * 4) = o;
    }
}

// ---------------- bf16 GEMM: C = A(MxK) @ W(NxK)^T + bias ----------------
template<bool OUT_BF16>
__global__ __launch_bounds__(256)
void gemm_bt(const __bf16* __restrict__ A, const __bf16* __restrict__ W,
             const float* __restrict__ bias, void* __restrict__ Cout,
             int M, int N, int K)
{
    __shared__ __bf16 As[128][72];   // +8 bf16 pad -> row stride 144B (kills bank conflict)
    __shared__ __bf16 Bs[128][72];
    const int tid  = threadIdx.x;
    const int m0   = blockIdx.y * 128;
    const int n0   = blockIdx.x * 128;
    const int wave = tid >> 6;
    const int lane = tid & 63;
    const int wr   = (wave >> 1) * 64;
    const int wc   = (wave & 1) * 64;
    const int lr   = lane & 15;
    const int lk   = (lane >> 4) * 8;
    const int srow = tid >> 3;          // 0..31
    const int scol = (tid & 7) * 8;     // 0..56

    f32x4 acc[4][4] = {};

    for (int k0 = 0; k0 < K; k0 += 64) {
        #pragma unroll
        for (int g = 0; g < 4; ++g) {
            const int r = srow + g * 32;
            *(int4*)(&As[r][scol]) = *(const int4*)(A + (size_t)(m0 + r) * K + k0 + scol);
            *(int4*)(&Bs[r][scol]) = *(const int4*)(W + (size_t)(n0 + r) * K + k0 + scol);
        }
        __syncthreads();
        #pragma unroll
        for (int ks = 0; ks < 2; ++ks) {
            bf16x8 af[4], bfr[4];
            #pragma unroll
            for (int m = 0; m < 4; ++m)
                af[m] = *(const bf16x8*)(&As[wr + m * 16 + lr][ks * 32 + lk]);
            #pragma unroll
            for (int n = 0; n < 4; ++n)
                bfr[n] = *(const bf16x8*)(&Bs[wc + n * 16 + lr][ks * 32 + lk]);
            #pragma unroll
            for (int m = 0; m < 4; ++m)
                #pragma unroll
                for (int n = 0; n < 4; ++n)
                    acc[m][n] = __builtin_amdgcn_mfma_f32_16x16x32_bf16(af[m], bfr[n], acc[m][n], 0, 0, 0);
        }
        __syncthreads();
    }

    const int orow = (lane >> 4) * 4;
    #pragma unroll
    for (int n = 0; n < 4; ++n) {
        const int col = n0 + wc + n * 16 + lr;
        const float bv = bias[col];
        #pragma unroll
        for (int m = 0; m < 4; ++m) {
            #pragma unroll
            for (int r = 0; r < 4; ++r) {
                const int row = m0 + wr + m * 16 + orow + r;
                const float v = acc[m][n][r] + bv;
                if (OUT_BF16) ((__bf16*)Cout)[(size_t)row * N + col] = (__bf16)v;
                else          ((float*)Cout)[(size_t)row * N + col]  = v;
            }
        }
    }
}

// ---------------- RoPE (in-place on bf16 q/k, layout (B,L,H*HD)) ----------------
__global__ void rope_k(__bf16* __restrict__ q, __bf16* __restrict__ k, const float* __restrict__ fc)
{
    __bf16* t = blockIdx.y ? k : q;
    const size_t e0 = ((size_t)blockIdx.x * blockDim.x + threadIdx.x) * 8;  // 4 pairs
    const int row = (int)(e0 >> 11);          // b*L + l
    const int l   = row & (LL - 1);
    const int din = (int)(e0 & (DD - 1));
    const int j0  = (din & (HDIM - 1)) >> 1;  // pair index within head (multiple of 4)
    bf16x8 v = *(bf16x8*)(t + e0);
    float4 c01 = *(const float4*)(fc + ((size_t)l * 64 + j0) * 2);
    float4 c23 = *(const float4*)(fc + ((size_t)l * 64 + j0 + 2) * 2);
    float cr[4] = { c01.x, c01.z, c23.x, c23.z };
    float ci[4] = { c01.y, c01.w, c23.y, c23.w };
    #pragma unroll
    for (int p = 0; p < 4; ++p) {
        float a = (float)v[2 * p], b = (float)v[2 * p + 1];
        v[2 * p]     = (__bf16)(a * cr[p] - b * ci[p]);
        v[2 * p + 1] = (__bf16)(a * ci[p] + b * cr[p]);
    }
    *(bf16x8*)(t + e0) = v;
}

// ---------------- latent projections: (b,h,l,:) 128 -> 32 ----------------
__global__ __launch_bounds__(256)
void latproj(const __bf16* __restrict__ qb, const __bf16* __restrict__ kb, const __bf16* __restrict__ vb,
             const float* __restrict__ Wq, const float* __restrict__ bq,
             const float* __restrict__ Wk, const float* __restrict__ bk,
             const float* __restrict__ Wv, const float* __restrict__ bv,
             float* __restrict__ qc, float* __restrict__ kc, float* __restrict__ vc)
{
    const int which = blockIdx.y;
    const __bf16* in = which == 0 ? qb : which == 1 ? kb : vb;
    const float*  W  = which == 0 ? Wq : which == 1 ? Wk : Wv;
    const float*  bs = which == 0 ? bq : which == 1 ? bk : bv;
    float*        out = which == 0 ? qc : which == 1 ? kc : vc;

    __shared__ float Ws[32][129];           // stride 129: conflict-free column reads
    for (int i = threadIdx.x; i < 32 * 128; i += 256)
        Ws[i >> 7][i & 127] = W[i];
    __syncthreads();

    const int o = threadIdx.x & 31;
    const int t = threadIdx.x >> 5;
    const size_t g = (size_t)blockIdx.x * 8 + t;   // (b*H + h)*L + l
    const int l  = (int)(g & (LL - 1));
    const int bh = (int)(g >> 11);
    const int h  = bh & (HH - 1);
    const int b  = bh >> 4;
    const __bf16* row = in + ((size_t)(b * LL + l) * DD + h * HDIM);
    float s = bs[o];
    #pragma unroll
    for (int d8 = 0; d8 < 16; ++d8) {
        bf16x8 rv = *(const bf16x8*)(row + d8 * 8);
        #pragma unroll
        for (int j = 0; j < 8; ++j)
            s += (float)rv[j] * Ws[o][d8 * 8 + j];
    }
    out[g * 32 + o] = s;
}

// ---------------- split-K causal flash attention, phase 1 (partials) ----------------
// grid (bh=32, qquad=8, chunk=4); 256 threads; 1 query/thread; chunk = 512 keys.
// Partials are UNNORMALIZED: (m, l, o[32]) with o = sum p*V, l = sum p.
__global__ __launch_bounds__(256)
void attn_part(const float* __restrict__ qc, const float* __restrict__ kc, const float* __restrict__ vc,
               float* __restrict__ pm, float* __restrict__ pl, float* __restrict__ po)
{
    const int bh = blockIdx.x;
    const int qq = blockIdx.y;
    const int c  = blockIdx.z;
    if (c * CHUNK > qq * 256 + 255) return;   // chunk beyond this quad's causal horizon

    __shared__ float Ks[64][36];
    __shared__ float Vs[64][36];
    const int tid = threadIdx.x;
    const int i   = qq * 256 + tid;          // query index within (b,h)
    const size_t base = (size_t)bh * LL * 32;
    const int k0   = c * CHUNK;
    const int kend = min(k0 + CHUNK, (qq + 1) * 256);
    const int nsub = (kend - k0) >> 6;       // 4 or 8 subtiles of 64 keys
    const float scale = 0.1767766952966369f; // 1/sqrt(32)

    float q[32];
    #pragma unroll
    for (int c4 = 0; c4 < 8; ++c4) {
        float4 v = *(const float4*)(qc + base + (size_t)i * 32 + c4 * 4);
        q[c4 * 4 + 0] = v.x; q[c4 * 4 + 1] = v.y; q[c4 * 4 + 2] = v.z; q[c4 * 4 + 3] = v.w;
    }
    float m = -1e30f, lsum = 0.f;
    float o[32] = {};

    const int srow = tid >> 2;
    const int sc   = (tid & 3) * 8;

    for (int sub = 0; sub < nsub; ++sub) {
        const int kbase = k0 + sub * 64;
        const float* kr = kc + base + (size_t)(kbase + srow) * 32 + sc;
        const float* vr = vc + base + (size_t)(kbase + srow) * 32 + sc;
        *(float4*)(&Ks[srow][sc])     = *(const float4*)kr;
        *(float4*)(&Ks[srow][sc + 4]) = *(const float4*)(kr + 4);
        *(float4*)(&Vs[srow][sc])     = *(const float4*)vr;
        *(float4*)(&Vs[srow][sc + 4]) = *(const float4*)(vr + 4);
        __syncthreads();

        if (kbase <= i) {                    // else: all 64 keys masked for this thread
            const bool anymask = (kbase + 63 > i);
            #pragma unroll 1
            for (int ch = 0; ch < 4; ++ch) {
                float s[16];
                #pragma unroll
                for (int r = 0; r < 16; ++r) {
                    const int rr = ch * 16 + r;
                    float a = 0.f;
                    #pragma unroll
                    for (int c4 = 0; c4 < 8; ++c4) {
                        float4 kv = *(const float4*)(&Ks[rr][c4 * 4]);
                        a += q[c4*4+0]*kv.x + q[c4*4+1]*kv.y + q[c4*4+2]*kv.z + q[c4*4+3]*kv.w;
                    }
                    s[r] = (anymask && (kbase + rr > i)) ? -2e30f : a * scale;
                }
                float tm = s[0];
                #pragma unroll
                for (int r = 1; r < 16; ++r) tm = fmaxf(tm, s[r]);
                const float nm = fmaxf(m, tm);
                const float f = __expf(m - nm);
                lsum *= f;
                #pragma unroll
                for (int d = 0; d < 32; ++d) o[d] *= f;
                m = nm;
                #pragma unroll
                for (int r = 0; r < 16; ++r) {
                    const float p = __expf(s[r] - m);
                    lsum += p;
                    const int rr = ch * 16 + r;
                    #pragma unroll
                    for (int c4 = 0; c4 < 8; ++c4) {
                        float4 vv = *(const float4*)(&Vs[rr][c4 * 4]);
                        o[c4*4+0] += p * vv.x; o[c4*4+1] += p * vv.y;
                        o[c4*4+2] += p * vv.z; o[c4*4+3] += p * vv.w;
                    }
                }
            }
        }
        __syncthreads();
    }

    const size_t g = (size_t)bh * LL + i;    // global query slot
    pm[g * 4 + c] = m;
    pl[g * 4 + c] = lsum;
    float* pp = po + (g * 4 + c) * 32;
    #pragma unroll
    for (int d4 = 0; d4 < 8; ++d4) {
        float4 t = { o[d4*4+0], o[d4*4+1], o[d4*4+2], o[d4*4+3] };
        *(float4*)(pp + d4 * 4) = t;
    }
}

// ---------------- split-K attention, phase 2 (combine) ----------------
__global__ __launch_bounds__(256)
void attn_comb(const float* __restrict__ pm, const float* __restrict__ pl,
               const float* __restrict__ po, float* __restrict__ ao)
{
    const int g = blockIdx.x * 256 + threadIdx.x;   // 0..65535
    const int i = g & (LL - 1);
    const int nch = ((i | 255) >> 9) + 1;           // chunks written for this query's quad
    float m = -1e30f;
    for (int c = 0; c < nch; ++c) m = fmaxf(m, pm[(size_t)g * 4 + c]);
    float L = 0.f;
    float o[32] = {};
    for (int c = 0; c < nch; ++c) {
        const float w = __expf(pm[(size_t)g * 4 + c] - m);
        L += w * pl[(size_t)g * 4 + c];
        const float* pp = po + ((size_t)g * 4 + c) * 32;
        #pragma unroll
        for (int d4 = 0; d4 < 8; ++d4) {
            float4 v = *(const float4*)(pp + d4 * 4);
            o[d4*4+0] += w * v.x; o[d4*4+1] += w * v.y;
            o[d4*4+2] += w * v.z; o[d4*4+3] += w * v.w;
        }
    }
    const float inv = 1.f / L;
    #pragma unroll
    for (int d4 = 0; d4 < 8; ++d4) {
        float4 v = { o[d4*4+0]*inv, o[d4*4+1]*inv, o[d4*4+2]*inv, o[d4*4+3]*inv };
        *(float4*)(ao + (size_t)g * 32 + d4 * 4) = v;
    }
}

// ---------------- decode latent 32 -> 128, write (B,L,D) bf16 ----------------
__global__ __launch_bounds__(256)
void wd_k(const float* __restrict__ ao, const float* __restrict__ Wd, const float* __restrict__ bd,
          __bf16* __restrict__ out)
{
    __shared__ float Ws[128][33];
    for (int i = threadIdx.x; i < 128 * 32; i += 256)
        Ws[i >> 5][i & 31] = Wd[i];
    __syncthreads();
    const int hd = threadIdx.x & 127;
    const int t  = threadIdx.x >> 7;
    const size_t g = (size_t)blockIdx.x * 2 + t;   // (b*H + h)*L + l
    const int l  = (int)(g & (LL - 1));
    const int bh = (int)(g >> 11);
    const int h  = bh & (HH - 1);
    const int b  = bh >> 4;
    const float* arow = ao + g * 32;
    float s = bd[hd];
    #pragma unroll
    for (int c4 = 0; c4 < 8; ++c4) {
        float4 av = *(const float4*)(arow + c4 * 4);
        s += av.x * Ws[hd][c4 * 4 + 0] + av.y * Ws[hd][c4 * 4 + 1]
           + av.z * Ws[hd][c4 * 4 + 2] + av.w * Ws[hd][c4 * 4 + 3];
    }
    out[(size_t)(b * LL + l) * DD + h * HDIM + hd] = (__bf16)s;
}

extern "C" void kernel_launch(void* const* d_in, const int* in_sizes, int n_in,
                              void* d_out, int out_size, void* d_ws, size_t ws_size,
                              hipStream_t stream)
{
    const float* x   = (const float*)d_in[0];
    const float* fc  = (const float*)d_in[1];
    const float* Wq  = (const float*)d_in[2];
    const float* bq  = (const float*)d_in[3];
    const float* Wk  = (const float*)d_in[4];
    const float* bk  = (const float*)d_in[5];
    const float* Wv  = (const float*)d_in[6];
    const float* bv  = (const float*)d_in[7];
    const float* Wqc = (const float*)d_in[8];
    const float* bqc = (const float*)d_in[9];
    const float* Wkc = (const float*)d_in[10];
    const float* bkc = (const float*)d_in[11];
    const float* Wvc = (const float*)d_in[12];
    const float* bvc = (const float*)d_in[13];
    const float* Wd  = (const float*)d_in[14];
    const float* bd  = (const float*)d_in[15];
    const float* Wo  = (const float*)d_in[16];
    const float* bo  = (const float*)d_in[17];
    float* out = (float*)d_out;

    // workspace layout (151 MB total)
    char* w = (char*)d_ws;
    __bf16* xb  = (__bf16*)w; w += (size_t)4096 * 2048 * 2;   // [0, 16M)
    __bf16* Wqb = (__bf16*)w; w += (size_t)2048 * 2048 * 2;   // [16M, 24M)
    __bf16* Wkb = (__bf16*)w; w += (size_t)2048 * 2048 * 2;   // [24M, 32M)
    __bf16* Wvb = (__bf16*)w; w += (size_t)2048 * 2048 * 2;   // [32M, 40M)
    __bf16* Wob = (__bf16*)w; w += (size_t)2048 * 2048 * 2;   // [40M, 48M)
    __bf16* qb  = (__bf16*)w; w += (size_t)4096 * 2048 * 2;
    __bf16* kb  = (__bf16*)w; w += (size_t)4096 * 2048 * 2;
    __bf16* vb  = (__bf16*)w; w += (size_t)4096 * 2048 * 2;
    float* qcb  = (float*)w;  w += (size_t)65536 * 32 * 4;
    float* kcb  = (float*)w;  w += (size_t)65536 * 32 * 4;
    float* vcb  = (float*)w;  w += (size_t)65536 * 32 * 4;
    float* aob  = (float*)w;  w += (size_t)65536 * 32 * 4;
    __bf16* adb = (__bf16*)w; w += (size_t)4096 * 2048 * 2;

    // attention partials alias xb..Wvb (dead after latproj): 35.7 MB < 40 MB
    float* po = (float*)d_ws;                               // 65536*4*32*4 = 33554432 B
    float* pm = (float*)((char*)d_ws + 33554432);           // 1 MB
    float* pl = (float*)((char*)d_ws + 34603008);           // 1 MB

    if (ws_size < (size_t)150994944) return;  // fail loudly (zero output) rather than corrupt

    cvt_f32_bf16<<<8192, 256, 0, stream>>>(x,  xb,  2097152);
    cvt_f32_bf16<<<4096, 256, 0, stream>>>(Wq, Wqb, 1048576);
    cvt_f32_bf16<<<4096, 256, 0, stream>>>(Wk, Wkb, 1048576);
    cvt_f32_bf16<<<4096, 256, 0, stream>>>(Wv, Wvb, 1048576);
    cvt_f32_bf16<<<4096, 256, 0, stream>>>(Wo, Wob, 1048576);

    dim3 ggrid(16, 32);
    gemm_bt<true><<<ggrid, 256, 0, stream>>>(xb, Wqb, bq, qb, 4096, 2048, 2048);
    gemm_bt<true><<<ggrid, 256, 0, stream>>>(xb, Wkb, bk, kb, 4096, 2048, 2048);
    gemm_bt<true><<<ggrid, 256, 0, stream>>>(xb, Wvb, bv, vb, 4096, 2048, 2048);

    rope_k<<<dim3(4096, 2), 256, 0, stream>>>(qb, kb, fc);

    latproj<<<dim3(8192, 3), 256, 0, stream>>>(qb, kb, vb, Wqc, bqc, Wkc, bkc, Wvc, bvc,
                                               qcb, kcb, vcb);

    attn_part<<<dim3(32, 8, 4), 256, 0, stream>>>(qcb, kcb, vcb, pm, pl, po);
    attn_comb<<<256, 256, 0, stream>>>(pm, pl, po, aob);

    wd_k<<<32768, 256, 0, stream>>>(aob, Wd, bd, adb);

    gemm_bt<false><<<ggrid, 256, 0, stream>>>(adb, Wob, bo, out, 4096, 2048, 2048);
}

// Round 3
// 453.437 us; speedup vs baseline: 2.8119x; 1.6982x over previous
//
#include <hip/hip_runtime.h>

typedef __attribute__((ext_vector_type(8))) __bf16 bf16x8;
typedef __attribute__((ext_vector_type(4))) __bf16 bf16x4;
typedef __attribute__((ext_vector_type(4))) float f32x4;
typedef __attribute__((ext_vector_type(16))) float f32x16;

#define LL 2048
#define DD 2048
#define HH 16
#define HDIM 128

// ---------------- fp32 -> bf16 conversion ----------------
__global__ void cvt_f32_bf16(const float* __restrict__ src, __bf16* __restrict__ dst, int n4)
{
    int i = blockIdx.x * blockDim.x + threadIdx.x;
    if (i < n4) {
        float4 v = *(const float4*)(src + (size_t)i * 4);
        bf16x4 o = { (__bf16)v.x, (__bf16)v.y, (__bf16)v.z, (__bf16)v.w };
        *(bf16x4*)(dst + (size_t)i * 4) = o;
    }
}

// ---------------- bf16 GEMM: C = A(MxK) @ W(NxK)^T + bias ----------------
template<bool OUT_BF16>
__global__ __launch_bounds__(256)
void gemm_bt(const __bf16* __restrict__ A, const __bf16* __restrict__ W,
             const float* __restrict__ bias, void* __restrict__ Cout,
             int M, int N, int K)
{
    __shared__ __bf16 As[128][72];   // +8 bf16 pad -> row stride 144B (kills bank conflict)
    __shared__ __bf16 Bs[128][72];
    const int tid  = threadIdx.x;
    const int m0   = blockIdx.y * 128;
    const int n0   = blockIdx.x * 128;
    const int wave = tid >> 6;
    const int lane = tid & 63;
    const int wr   = (wave >> 1) * 64;
    const int wc   = (wave & 1) * 64;
    const int lr   = lane & 15;
    const int lk   = (lane >> 4) * 8;
    const int srow = tid >> 3;          // 0..31
    const int scol = (tid & 7) * 8;     // 0..56

    f32x4 acc[4][4] = {};

    for (int k0 = 0; k0 < K; k0 += 64) {
        #pragma unroll
        for (int g = 0; g < 4; ++g) {
            const int r = srow + g * 32;
            *(int4*)(&As[r][scol]) = *(const int4*)(A + (size_t)(m0 + r) * K + k0 + scol);
            *(int4*)(&Bs[r][scol]) = *(const int4*)(W + (size_t)(n0 + r) * K + k0 + scol);
        }
        __syncthreads();
        #pragma unroll
        for (int ks = 0; ks < 2; ++ks) {
            bf16x8 af[4], bfr[4];
            #pragma unroll
            for (int m = 0; m < 4; ++m)
                af[m] = *(const bf16x8*)(&As[wr + m * 16 + lr][ks * 32 + lk]);
            #pragma unroll
            for (int n = 0; n < 4; ++n)
                bfr[n] = *(const bf16x8*)(&Bs[wc + n * 16 + lr][ks * 32 + lk]);
            #pragma unroll
            for (int m = 0; m < 4; ++m)
                #pragma unroll
                for (int n = 0; n < 4; ++n)
                    acc[m][n] = __builtin_amdgcn_mfma_f32_16x16x32_bf16(af[m], bfr[n], acc[m][n], 0, 0, 0);
        }
        __syncthreads();
    }

    const int orow = (lane >> 4) * 4;
    #pragma unroll
    for (int n = 0; n < 4; ++n) {
        const int col = n0 + wc + n * 16 + lr;
        const float bv = bias[col];
        #pragma unroll
        for (int m = 0; m < 4; ++m) {
            #pragma unroll
            for (int r = 0; r < 4; ++r) {
                const int row = m0 + wr + m * 16 + orow + r;
                const float v = acc[m][n][r] + bv;
                if (OUT_BF16) ((__bf16*)Cout)[(size_t)row * N + col] = (__bf16)v;
                else          ((float*)Cout)[(size_t)row * N + col]  = v;
            }
        }
    }
}

// ---------------- RoPE (in-place on bf16 q/k, layout (B,L,H*HD)) ----------------
__global__ void rope_k(__bf16* __restrict__ q, __bf16* __restrict__ k, const float* __restrict__ fc)
{
    __bf16* t = blockIdx.y ? k : q;
    const size_t e0 = ((size_t)blockIdx.x * blockDim.x + threadIdx.x) * 8;  // 4 pairs
    const int row = (int)(e0 >> 11);          // b*L + l
    const int l   = row & (LL - 1);
    const int j0  = (int)((e0 & (HDIM - 1)) >> 1);  // pair index within head
    bf16x8 v = *(bf16x8*)(t + e0);
    float4 c01 = *(const float4*)(fc + ((size_t)l * 64 + j0) * 2);
    float4 c23 = *(const float4*)(fc + ((size_t)l * 64 + j0 + 2) * 2);
    float cr[4] = { c01.x, c01.z, c23.x, c23.z };
    float ci[4] = { c01.y, c01.w, c23.y, c23.w };
    #pragma unroll
    for (int p = 0; p < 4; ++p) {
        float a = (float)v[2 * p], b = (float)v[2 * p + 1];
        v[2 * p]     = (__bf16)(a * cr[p] - b * ci[p]);
        v[2 * p + 1] = (__bf16)(a * ci[p] + b * cr[p]);
    }
    *(bf16x8*)(t + e0) = v;
}

// ---------------- latent projections: (b,h,l,:) 128 -> 32, bf16 out ----------------
// q: scaled by 1/sqrt(LAT)*log2(e) (folded softmax scale, log2 domain)
// v: written TRANSPOSED vt[bh][dim][l] for the attention PV A-operand.
__global__ __launch_bounds__(256)
void latproj(const __bf16* __restrict__ qb, const __bf16* __restrict__ kb, const __bf16* __restrict__ vb,
             const float* __restrict__ Wq, const float* __restrict__ bq,
             const float* __restrict__ Wk, const float* __restrict__ bk,
             const float* __restrict__ Wv, const float* __restrict__ bv,
             __bf16* __restrict__ qc, __bf16* __restrict__ kc, __bf16* __restrict__ vt)
{
    const int which = blockIdx.y;
    const __bf16* in = which == 0 ? qb : which == 1 ? kb : vb;
    const float*  W  = which == 0 ? Wq : which == 1 ? Wk : Wv;
    const float*  bs = which == 0 ? bq : which == 1 ? bk : bv;

    __shared__ float Ws[32][129];           // stride 129: conflict-free column reads
    for (int i = threadIdx.x; i < 32 * 128; i += 256)
        Ws[i >> 7][i & 127] = W[i];
    __syncthreads();

    const int o = threadIdx.x & 31;
    const int t = threadIdx.x >> 5;
    const size_t g = (size_t)blockIdx.x * 8 + t;   // (b*H + h)*L + l
    const int l  = (int)(g & (LL - 1));
    const int bh = (int)(g >> 11);
    const int h  = bh & (HH - 1);
    const int b  = bh >> 4;
    const __bf16* row = in + ((size_t)(b * LL + l) * DD + h * HDIM);
    float s = bs[o];
    #pragma unroll
    for (int d8 = 0; d8 < 16; ++d8) {
        bf16x8 rv = *(const bf16x8*)(row + d8 * 8);
        #pragma unroll
        for (int j = 0; j < 8; ++j)
            s += (float)rv[j] * Ws[o][d8 * 8 + j];
    }
    const float QSCALE = 0.17677669529663689f * 1.44269504088896340f;
    if (which == 0)      qc[g * 32 + o] = (__bf16)(s * QSCALE);
    else if (which == 1) kc[g * 32 + o] = (__bf16)s;
    else                 vt[((size_t)bh * 32 + o) * LL + l] = (__bf16)s;
}

// ---------------- helpers for MFMA attention ----------------
__device__ __forceinline__ unsigned pkbf2(float a, float b)
{
    union { __bf16 h[2]; unsigned u; } x;
    x.h[0] = (__bf16)a; x.h[1] = (__bf16)b;
    return x.u;
}

#if __has_builtin(__builtin_amdgcn_permlane32_swap)
typedef unsigned int uint2v __attribute__((ext_vector_type(2)));
__device__ __forceinline__ void plswap(unsigned a, unsigned b, unsigned& w_lo, unsigned& w_hi, int)
{
    uint2v r = __builtin_amdgcn_permlane32_swap(a, b, false, false);
    w_lo = r[0]; w_hi = r[1];
}
#else
__device__ __forceinline__ void plswap(unsigned a, unsigned b, unsigned& w_lo, unsigned& w_hi, int hi)
{
    unsigned ax = (unsigned)__shfl_xor((int)a, 32);
    unsigned bx = (unsigned)__shfl_xor((int)b, 32);
    w_lo = hi ? bx : a;
    w_hi = hi ? b  : ax;
}
#endif

// ---------------- causal flash attention via MFMA (swapped QK^T, T12) --------
// 1 wave per 32-query strip. S^T = mfma(K, Q): lane owns query col = lane&31,
// key rows (r&3)+8*(r>>2)+4*(lane>>5). No LDS, no barriers.
__global__ __launch_bounds__(64)
void attn_mfma(const __bf16* __restrict__ qc, const __bf16* __restrict__ kc,
               const __bf16* __restrict__ vt, float* __restrict__ ao)
{
    const int s    = blockIdx.x;        // strip: queries [s*32, s*32+32)
    const int bh   = blockIdx.y;
    const int lane = threadIdx.x;
    const int qcol = lane & 31;
    const int hi   = lane >> 5;

    const __bf16* qbase = qc + ((size_t)bh * LL + (size_t)s * 32) * 32;
    const __bf16* kbase = kc + (size_t)bh * LL * 32;
    const __bf16* vbase = vt + (size_t)bh * 32 * LL;

    // Q as B-operand: lane holds col=query=qcol, k=dim=hi*8+j (frag0: dims 0-15, frag1: 16-31)
    const bf16x8 qf0 = *(const bf16x8*)(qbase + qcol * 32 + hi * 8);
    const bf16x8 qf1 = *(const bf16x8*)(qbase + qcol * 32 + 16 + hi * 8);

    float m = -1e30f, lsum = 0.f;
    f32x16 O = {};

    for (int t = 0; t <= s; ++t) {
        const int k0 = t * 32;
        // K as A-operand: row=key=k0+qcol(lane&31), k=dim
        const __bf16* krow = kbase + (size_t)(k0 + qcol) * 32 + hi * 8;
        const bf16x8 kf0 = *(const bf16x8*)(krow);
        const bf16x8 kf1 = *(const bf16x8*)(krow + 16);
        // V^T as A-operand: row=dim=qcol, k=key (frag0: keys k0+0..15, frag1: +16)
        const __bf16* vrow = vbase + (size_t)qcol * LL + k0 + hi * 8;
        const bf16x8 vf0 = *(const bf16x8*)(vrow);
        const bf16x8 vf1 = *(const bf16x8*)(vrow + 16);

        f32x16 S = {};
        S = __builtin_amdgcn_mfma_f32_32x32x16_bf16(kf0, qf0, S, 0, 0, 0);
        S = __builtin_amdgcn_mfma_f32_32x32x16_bf16(kf1, qf1, S, 0, 0, 0);

        if (t == s) {    // diagonal tile: mask key_local > query_local
            #pragma unroll
            for (int r = 0; r < 16; ++r) {
                const int kl = (r & 3) + 8 * (r >> 2) + 4 * hi;
                if (kl > qcol) S[r] = -1e30f;
            }
        }
        float tm = S[0];
        #pragma unroll
        for (int r = 1; r < 16; ++r) tm = fmaxf(tm, S[r]);
        tm = fmaxf(tm, __shfl_xor(tm, 32));
        const float mn = fmaxf(m, tm);
        const float fr = exp2f(m - mn);
        m = mn;
        float p[16]; float ls = 0.f;
        #pragma unroll
        for (int r = 0; r < 16; ++r) { p[r] = exp2f(S[r] - m); ls += p[r]; }
        lsum = lsum * fr + ls;
        #pragma unroll
        for (int r = 0; r < 16; ++r) O[r] *= fr;

        // repack P (scores) into PV B-operand fragments via permlane32_swap
        unsigned w[8];
        #pragma unroll
        for (int i = 0; i < 8; ++i) w[i] = pkbf2(p[2 * i], p[2 * i + 1]);
        union PF { unsigned u[4]; bf16x8 v; } pf1, pf2;
        plswap(w[0], w[2], pf1.u[0], pf1.u[2], hi);
        plswap(w[1], w[3], pf1.u[1], pf1.u[3], hi);
        plswap(w[4], w[6], pf2.u[0], pf2.u[2], hi);
        plswap(w[5], w[7], pf2.u[1], pf2.u[3], hi);

        O = __builtin_amdgcn_mfma_f32_32x32x16_bf16(vf0, pf1.v, O, 0, 0, 0);
        O = __builtin_amdgcn_mfma_f32_32x32x16_bf16(vf1, pf2.v, O, 0, 0, 0);
    }

    const float Ltot = lsum + __shfl_xor(lsum, 32);
    const float inv  = 1.f / Ltot;
    float* arow = ao + ((size_t)bh * LL + (size_t)s * 32 + qcol) * 32;
    #pragma unroll
    for (int g4 = 0; g4 < 4; ++g4) {   // dims (g4*8 + 4*hi) .. +3
        float4 v = { O[g4 * 4 + 0] * inv, O[g4 * 4 + 1] * inv,
                     O[g4 * 4 + 2] * inv, O[g4 * 4 + 3] * inv };
        *(float4*)(arow + g4 * 8 + 4 * hi) = v;
    }
}

// ---------------- decode latent 32 -> 128, write (B,L,D) bf16 ----------------
__global__ __launch_bounds__(256)
void wd_k(const float* __restrict__ ao, const float* __restrict__ Wd, const float* __restrict__ bd,
          __bf16* __restrict__ out)
{
    __shared__ float Ws[128][33];
    for (int i = threadIdx.x; i < 128 * 32; i += 256)
        Ws[i >> 5][i & 31] = Wd[i];
    __syncthreads();
    const int hd = threadIdx.x & 127;
    const int t  = threadIdx.x >> 7;
    const size_t g = (size_t)blockIdx.x * 2 + t;   // (b*H + h)*L + l
    const int l  = (int)(g & (LL - 1));
    const int bh = (int)(g >> 11);
    const int h  = bh & (HH - 1);
    const int b  = bh >> 4;
    const float* arow = ao + g * 32;
    float s = bd[hd];
    #pragma unroll
    for (int c4 = 0; c4 < 8; ++c4) {
        float4 av = *(const float4*)(arow + c4 * 4);
        s += av.x * Ws[hd][c4 * 4 + 0] + av.y * Ws[hd][c4 * 4 + 1]
           + av.z * Ws[hd][c4 * 4 + 2] + av.w * Ws[hd][c4 * 4 + 3];
    }
    out[(size_t)(b * LL + l) * DD + h * HDIM + hd] = (__bf16)s;
}

extern "C" void kernel_launch(void* const* d_in, const int* in_sizes, int n_in,
                              void* d_out, int out_size, void* d_ws, size_t ws_size,
                              hipStream_t stream)
{
    const float* x   = (const float*)d_in[0];
    const float* fc  = (const float*)d_in[1];
    const float* Wq  = (const float*)d_in[2];
    const float* bq  = (const float*)d_in[3];
    const float* Wk  = (const float*)d_in[4];
    const float* bk  = (const float*)d_in[5];
    const float* Wv  = (const float*)d_in[6];
    const float* bv  = (const float*)d_in[7];
    const float* Wqc = (const float*)d_in[8];
    const float* bqc = (const float*)d_in[9];
    const float* Wkc = (const float*)d_in[10];
    const float* bkc = (const float*)d_in[11];
    const float* Wvc = (const float*)d_in[12];
    const float* bvc = (const float*)d_in[13];
    const float* Wd  = (const float*)d_in[14];
    const float* bd  = (const float*)d_in[15];
    const float* Wo  = (const float*)d_in[16];
    const float* bo  = (const float*)d_in[17];
    float* out = (float*)d_out;

    // workspace layout (151 MB total)
    char* w = (char*)d_ws;
    __bf16* xb  = (__bf16*)w; w += (size_t)4096 * 2048 * 2;
    __bf16* Wqb = (__bf16*)w; w += (size_t)2048 * 2048 * 2;
    __bf16* Wkb = (__bf16*)w; w += (size_t)2048 * 2048 * 2;
    __bf16* Wvb = (__bf16*)w; w += (size_t)2048 * 2048 * 2;
    __bf16* Wob = (__bf16*)w; w += (size_t)2048 * 2048 * 2;
    __bf16* qb  = (__bf16*)w; w += (size_t)4096 * 2048 * 2;
    __bf16* kb  = (__bf16*)w; w += (size_t)4096 * 2048 * 2;
    __bf16* vb  = (__bf16*)w; w += (size_t)4096 * 2048 * 2;
    __bf16* qcbf = (__bf16*)w; w += (size_t)65536 * 32 * 4;  // bf16 in f32-sized slot
    __bf16* kcbf = (__bf16*)w; w += (size_t)65536 * 32 * 4;
    __bf16* vtbf = (__bf16*)w; w += (size_t)65536 * 32 * 4;
    float*  aob  = (float*)w;  w += (size_t)65536 * 32 * 4;
    __bf16* adb = (__bf16*)w;  w += (size_t)4096 * 2048 * 2;

    if (ws_size < (size_t)150994944) return;  // fail loudly (zero output) rather than corrupt

    cvt_f32_bf16<<<8192, 256, 0, stream>>>(x,  xb,  2097152);
    cvt_f32_bf16<<<4096, 256, 0, stream>>>(Wq, Wqb, 1048576);
    cvt_f32_bf16<<<4096, 256, 0, stream>>>(Wk, Wkb, 1048576);
    cvt_f32_bf16<<<4096, 256, 0, stream>>>(Wv, Wvb, 1048576);
    cvt_f32_bf16<<<4096, 256, 0, stream>>>(Wo, Wob, 1048576);

    dim3 ggrid(16, 32);
    gemm_bt<true><<<ggrid, 256, 0, stream>>>(xb, Wqb, bq, qb, 4096, 2048, 2048);
    gemm_bt<true><<<ggrid, 256, 0, stream>>>(xb, Wkb, bk, kb, 4096, 2048, 2048);
    gemm_bt<true><<<ggrid, 256, 0, stream>>>(xb, Wvb, bv, vb, 4096, 2048, 2048);

    rope_k<<<dim3(4096, 2), 256, 0, stream>>>(qb, kb, fc);

    latproj<<<dim3(8192, 3), 256, 0, stream>>>(qb, kb, vb, Wqc, bqc, Wkc, bkc, Wvc, bvc,
                                               qcbf, kcbf, vtbf);

    attn_mfma<<<dim3(64, 32), 64, 0, stream>>>(qcbf, kcbf, vtbf, aob);

    wd_k<<<32768, 256, 0, stream>>>(aob, Wd, bd, adb);

    gemm_bt<false><<<ggrid, 256, 0, stream>>>(adb, Wob, bo, out, 4096, 2048, 2048);
}

// Round 4
// 428.895 us; speedup vs baseline: 2.9728x; 1.0572x over previous
//
#include <hip/hip_runtime.h>

typedef __attribute__((ext_vector_type(8))) __bf16 bf16x8;
typedef __attribute__((ext_vector_type(4))) __bf16 bf16x4;
typedef __attribute__((ext_vector_type(4))) float f32x4;
typedef __attribute__((ext_vector_type(16))) float f32x16;

#define LL 2048
#define DD 2048
#define HH 16
#define HDIM 128

// ---------------- fp32 -> bf16 conversion ----------------
__global__ void cvt_f32_bf16(const float* __restrict__ src, __bf16* __restrict__ dst, int n4)
{
    int i = blockIdx.x * blockDim.x + threadIdx.x;
    if (i < n4) {
        float4 v = *(const float4*)(src + (size_t)i * 4);
        bf16x4 o = { (__bf16)v.x, (__bf16)v.y, (__bf16)v.z, (__bf16)v.w };
        *(bf16x4*)(dst + (size_t)i * 4) = o;
    }
}

// ---------------- global -> LDS async 16B ----------------
typedef unsigned int u32;
typedef const __attribute__((address_space(1))) u32* gp_t;
typedef __attribute__((address_space(3))) u32* lp_t;
__device__ __forceinline__ void gload16(const __bf16* g, __bf16* l)
{
    __builtin_amdgcn_global_load_lds((gp_t)(const void*)g, (lp_t)(void*)l, 16, 0, 0);
}

// ---------------- bf16 GEMM (m97 structure): C = A(MxK) @ W(NxK)^T + bias ----
// 128x128 tile, BK=64, 4 waves (2x2), linear LDS, global_load_lds width-16.
template<bool OUT_BF16>
__global__ __launch_bounds__(256)
void gemm_bt(const __bf16* __restrict__ A, const __bf16* __restrict__ W,
             const float* __restrict__ bias, void* __restrict__ Cout,
             int M, int N, int K)
{
    __shared__ __bf16 As[128][64];
    __shared__ __bf16 Bs[128][64];
    const int tid  = threadIdx.x;
    const int m0   = blockIdx.y * 128;
    const int n0   = blockIdx.x * 128;
    const int wave = tid >> 6;
    const int lane = tid & 63;
    const int wr   = (wave >> 1) * 64;
    const int wc   = (wave & 1) * 64;
    const int lr   = lane & 15;
    const int lk   = (lane >> 4) * 8;
    // staging: wave w covers rows [w*32, w*32+32), 4 chunks of 8 rows x 64 cols
    const int srow = wave * 32 + (lane >> 3);
    const int scol = (lane & 7) * 8;

    f32x4 acc[4][4] = {};
    const __bf16* Aw = A + (size_t)(m0 + srow) * K + scol;
    const __bf16* Ww = W + (size_t)(n0 + srow) * K + scol;
    __bf16* lA = &As[wave * 32][0];    // wave-uniform base; HW adds lane*16B
    __bf16* lB = &Bs[wave * 32][0];

    for (int k0 = 0; k0 < K; k0 += 64) {
        #pragma unroll
        for (int j = 0; j < 4; ++j) {
            gload16(Aw + (size_t)(j * 8) * K + k0, lA + j * 512);
            gload16(Ww + (size_t)(j * 8) * K + k0, lB + j * 512);
        }
        __syncthreads();
        #pragma unroll
        for (int ks = 0; ks < 2; ++ks) {
            bf16x8 af[4], bfr[4];
            #pragma unroll
            for (int m = 0; m < 4; ++m)
                af[m] = *(const bf16x8*)(&As[wr + m * 16 + lr][ks * 32 + lk]);
            #pragma unroll
            for (int n = 0; n < 4; ++n)
                bfr[n] = *(const bf16x8*)(&Bs[wc + n * 16 + lr][ks * 32 + lk]);
            #pragma unroll
            for (int m = 0; m < 4; ++m)
                #pragma unroll
                for (int n = 0; n < 4; ++n)
                    acc[m][n] = __builtin_amdgcn_mfma_f32_16x16x32_bf16(af[m], bfr[n], acc[m][n], 0, 0, 0);
        }
        __syncthreads();
    }

    const int orow = (lane >> 4) * 4;
    #pragma unroll
    for (int n = 0; n < 4; ++n) {
        const int col = n0 + wc + n * 16 + lr;
        const float bv = bias[col];
        #pragma unroll
        for (int m = 0; m < 4; ++m) {
            #pragma unroll
            for (int r = 0; r < 4; ++r) {
                const int row = m0 + wr + m * 16 + orow + r;
                const float v = acc[m][n][r] + bv;
                if (OUT_BF16) ((__bf16*)Cout)[(size_t)row * N + col] = (__bf16)v;
                else          ((float*)Cout)[(size_t)row * N + col]  = v;
            }
        }
    }
}

// ---------------- RoPE (in-place on bf16 q/k, layout (B,L,H*HD)) ----------------
__global__ void rope_k(__bf16* __restrict__ q, __bf16* __restrict__ k, const float* __restrict__ fc)
{
    __bf16* t = blockIdx.y ? k : q;
    const size_t e0 = ((size_t)blockIdx.x * blockDim.x + threadIdx.x) * 8;  // 4 pairs
    const int row = (int)(e0 >> 11);          // b*L + l
    const int l   = row & (LL - 1);
    const int j0  = (int)((e0 & (HDIM - 1)) >> 1);  // pair index within head
    bf16x8 v = *(bf16x8*)(t + e0);
    float4 c01 = *(const float4*)(fc + ((size_t)l * 64 + j0) * 2);
    float4 c23 = *(const float4*)(fc + ((size_t)l * 64 + j0 + 2) * 2);
    float cr[4] = { c01.x, c01.z, c23.x, c23.z };
    float ci[4] = { c01.y, c01.w, c23.y, c23.w };
    #pragma unroll
    for (int p = 0; p < 4; ++p) {
        float a = (float)v[2 * p], b = (float)v[2 * p + 1];
        v[2 * p]     = (__bf16)(a * cr[p] - b * ci[p]);
        v[2 * p + 1] = (__bf16)(a * ci[p] + b * cr[p]);
    }
    *(bf16x8*)(t + e0) = v;
}

// ---------------- latent projections: (b,h,l,:) 128 -> 32, bf16 out ----------------
// q: scaled by 1/sqrt(LAT)*log2(e) (folded softmax scale, log2 domain)
// v: written TRANSPOSED vt[bh][dim][l] for the attention PV A-operand.
__global__ __launch_bounds__(256)
void latproj(const __bf16* __restrict__ qb, const __bf16* __restrict__ kb, const __bf16* __restrict__ vb,
             const float* __restrict__ Wq, const float* __restrict__ bq,
             const float* __restrict__ Wk, const float* __restrict__ bk,
             const float* __restrict__ Wv, const float* __restrict__ bv,
             __bf16* __restrict__ qc, __bf16* __restrict__ kc, __bf16* __restrict__ vt)
{
    const int which = blockIdx.y;
    const __bf16* in = which == 0 ? qb : which == 1 ? kb : vb;
    const float*  W  = which == 0 ? Wq : which == 1 ? Wk : Wv;
    const float*  bs = which == 0 ? bq : which == 1 ? bk : bv;

    __shared__ float Ws[32][129];           // stride 129: conflict-free column reads
    for (int i = threadIdx.x; i < 32 * 128; i += 256)
        Ws[i >> 7][i & 127] = W[i];
    __syncthreads();

    const int o = threadIdx.x & 31;
    const int t = threadIdx.x >> 5;
    const size_t g = (size_t)blockIdx.x * 8 + t;   // (b*H + h)*L + l
    const int l  = (int)(g & (LL - 1));
    const int bh = (int)(g >> 11);
    const int h  = bh & (HH - 1);
    const int b  = bh >> 4;
    const __bf16* row = in + ((size_t)(b * LL + l) * DD + h * HDIM);
    float s = bs[o];
    #pragma unroll
    for (int d8 = 0; d8 < 16; ++d8) {
        bf16x8 rv = *(const bf16x8*)(row + d8 * 8);
        #pragma unroll
        for (int j = 0; j < 8; ++j)
            s += (float)rv[j] * Ws[o][d8 * 8 + j];
    }
    const float QSCALE = 0.17677669529663689f * 1.44269504088896340f;
    if (which == 0)      qc[g * 32 + o] = (__bf16)(s * QSCALE);
    else if (which == 1) kc[g * 32 + o] = (__bf16)s;
    else                 vt[((size_t)bh * 32 + o) * LL + l] = (__bf16)s;
}

// ---------------- helpers for MFMA attention ----------------
__device__ __forceinline__ unsigned pkbf2(float a, float b)
{
    union { __bf16 h[2]; unsigned u; } x;
    x.h[0] = (__bf16)a; x.h[1] = (__bf16)b;
    return x.u;
}

#if __has_builtin(__builtin_amdgcn_permlane32_swap)
typedef unsigned int uint2v __attribute__((ext_vector_type(2)));
__device__ __forceinline__ void plswap(unsigned a, unsigned b, unsigned& w_lo, unsigned& w_hi, int)
{
    uint2v r = __builtin_amdgcn_permlane32_swap(a, b, false, false);
    w_lo = r[0]; w_hi = r[1];
}
#else
__device__ __forceinline__ void plswap(unsigned a, unsigned b, unsigned& w_lo, unsigned& w_hi, int hi)
{
    unsigned ax = (unsigned)__shfl_xor((int)a, 32);
    unsigned bx = (unsigned)__shfl_xor((int)b, 32);
    w_lo = hi ? bx : a;
    w_hi = hi ? b  : ax;
}
#endif

// ---------------- split-K causal flash attention via MFMA ----------------
// One wave per (bh, 32-query strip, 512-key chunk). Partials in log2 domain.
// Grid is 1D, id%8 == bh%8 so same-bh waves share an XCD's L2.
__global__ __launch_bounds__(64)
void attn_part(const __bf16* __restrict__ qc, const __bf16* __restrict__ kc,
               const __bf16* __restrict__ vt,
               float* __restrict__ pm, float* __restrict__ pl, float* __restrict__ po)
{
    const int id  = blockIdx.x;
    const int bhl = id & 7;
    const int c   = id >> 3;
    const int bhh = c / 160;
    const int lin = c - bhh * 160;
    int s, ci;
    if (lin < 16)      { s = lin; ci = 0; }
    else if (lin < 48) { int q = lin - 16; s = 16 + (q >> 1); ci = q & 1; }
    else if (lin < 96) { int q = lin - 48; int d = q / 3; s = 32 + d; ci = q - d * 3; }
    else               { int q = lin - 96; s = 48 + (q >> 2); ci = q & 3; }
    const int bh = bhh * 8 + bhl;

    const int lane = threadIdx.x;
    const int qcol = lane & 31;
    const int hi   = lane >> 5;

    const __bf16* qbase = qc + ((size_t)bh * LL + (size_t)s * 32) * 32;
    const __bf16* kbase = kc + (size_t)bh * LL * 32;
    const __bf16* vbase = vt + (size_t)bh * 32 * LL;

    const bf16x8 qf0 = *(const bf16x8*)(qbase + qcol * 32 + hi * 8);
    const bf16x8 qf1 = *(const bf16x8*)(qbase + qcol * 32 + 16 + hi * 8);

    float m = -1e30f, lsum = 0.f;
    f32x16 O = {};

    const int t0 = ci * 16;
    const int t1 = min(s, t0 + 15);

    // prefetch tile t0
    const __bf16* krow = kbase + (size_t)(t0 * 32 + qcol) * 32 + hi * 8;
    const __bf16* vrow = vbase + (size_t)qcol * LL + t0 * 32 + hi * 8;
    bf16x8 kc0 = *(const bf16x8*)(krow);
    bf16x8 kc1 = *(const bf16x8*)(krow + 16);
    bf16x8 vc0 = *(const bf16x8*)(vrow);
    bf16x8 vc1 = *(const bf16x8*)(vrow + 16);

    for (int t = t0; t <= t1; ++t) {
        // prefetch next tile (clamped re-load of current on last iter)
        const int tn = (t < t1) ? t + 1 : t;
        const __bf16* krn = kbase + (size_t)(tn * 32 + qcol) * 32 + hi * 8;
        const __bf16* vrn = vbase + (size_t)qcol * LL + tn * 32 + hi * 8;
        bf16x8 kn0 = *(const bf16x8*)(krn);
        bf16x8 kn1 = *(const bf16x8*)(krn + 16);
        bf16x8 vn0 = *(const bf16x8*)(vrn);
        bf16x8 vn1 = *(const bf16x8*)(vrn + 16);

        f32x16 S = {};
        S = __builtin_amdgcn_mfma_f32_32x32x16_bf16(kc0, qf0, S, 0, 0, 0);
        S = __builtin_amdgcn_mfma_f32_32x32x16_bf16(kc1, qf1, S, 0, 0, 0);

        if (t == s) {    // diagonal tile: mask key_local > query_local
            #pragma unroll
            for (int r = 0; r < 16; ++r) {
                const int kl = (r & 3) + 8 * (r >> 2) + 4 * hi;
                if (kl > qcol) S[r] = -1e30f;
            }
        }
        float tm = S[0];
        #pragma unroll
        for (int r = 1; r < 16; ++r) tm = fmaxf(tm, S[r]);
        tm = fmaxf(tm, __shfl_xor(tm, 32));
        const float mn = fmaxf(m, tm);
        const float fr = exp2f(m - mn);
        m = mn;
        float p[16]; float ls = 0.f;
        #pragma unroll
        for (int r = 0; r < 16; ++r) { p[r] = exp2f(S[r] - m); ls += p[r]; }
        lsum = lsum * fr + ls;
        #pragma unroll
        for (int r = 0; r < 16; ++r) O[r] *= fr;

        unsigned w[8];
        #pragma unroll
        for (int i = 0; i < 8; ++i) w[i] = pkbf2(p[2 * i], p[2 * i + 1]);
        union PF { unsigned u[4]; bf16x8 v; } pf1, pf2;
        plswap(w[0], w[2], pf1.u[0], pf1.u[2], hi);
        plswap(w[1], w[3], pf1.u[1], pf1.u[3], hi);
        plswap(w[4], w[6], pf2.u[0], pf2.u[2], hi);
        plswap(w[5], w[7], pf2.u[1], pf2.u[3], hi);

        O = __builtin_amdgcn_mfma_f32_32x32x16_bf16(vc0, pf1.v, O, 0, 0, 0);
        O = __builtin_amdgcn_mfma_f32_32x32x16_bf16(vc1, pf2.v, O, 0, 0, 0);

        kc0 = kn0; kc1 = kn1; vc0 = vn0; vc1 = vn1;
    }

    const float L = lsum + __shfl_xor(lsum, 32);
    const size_t g = (size_t)bh * LL + (size_t)s * 32 + qcol;
    const size_t slot = g * 4 + ci;
    if (hi == 0) { pm[slot] = m; pl[slot] = L; }
    float* pp = po + slot * 32;
    #pragma unroll
    for (int g4 = 0; g4 < 4; ++g4) {
        float4 v = { O[g4 * 4 + 0], O[g4 * 4 + 1], O[g4 * 4 + 2], O[g4 * 4 + 3] };
        *(float4*)(pp + g4 * 8 + 4 * hi) = v;
    }
}

// ---------------- split-K attention combine (log2-domain partials) ----------
__global__ __launch_bounds__(256)
void attn_comb(const float* __restrict__ pm, const float* __restrict__ pl,
               const float* __restrict__ po, float* __restrict__ ao)
{
    const int g = blockIdx.x * 256 + threadIdx.x;   // 0..65535
    const int i = g & (LL - 1);
    const int nch = (i >> 9) + 1;
    float m = -1e30f;
    for (int c = 0; c < nch; ++c) m = fmaxf(m, pm[(size_t)g * 4 + c]);
    float L = 0.f;
    float o[32] = {};
    for (int c = 0; c < nch; ++c) {
        const float w = exp2f(pm[(size_t)g * 4 + c] - m);
        L += w * pl[(size_t)g * 4 + c];
        const float* pp = po + ((size_t)g * 4 + c) * 32;
        #pragma unroll
        for (int d4 = 0; d4 < 8; ++d4) {
            float4 v = *(const float4*)(pp + d4 * 4);
            o[d4*4+0] += w * v.x; o[d4*4+1] += w * v.y;
            o[d4*4+2] += w * v.z; o[d4*4+3] += w * v.w;
        }
    }
    const float inv = 1.f / L;
    #pragma unroll
    for (int d4 = 0; d4 < 8; ++d4) {
        float4 v = { o[d4*4+0]*inv, o[d4*4+1]*inv, o[d4*4+2]*inv, o[d4*4+3]*inv };
        *(float4*)(ao + (size_t)g * 32 + d4 * 4) = v;
    }
}

// ---------------- decode latent 32 -> 128, write (B,L,D) bf16 ----------------
__global__ __launch_bounds__(256)
void wd_k(const float* __restrict__ ao, const float* __restrict__ Wd, const float* __restrict__ bd,
          __bf16* __restrict__ out)
{
    __shared__ float Ws[128][33];
    for (int i = threadIdx.x; i < 128 * 32; i += 256)
        Ws[i >> 5][i & 31] = Wd[i];
    __syncthreads();
    const int hd = threadIdx.x & 127;
    const int t  = threadIdx.x >> 7;
    const size_t g = (size_t)blockIdx.x * 2 + t;   // (b*H + h)*L + l
    const int l  = (int)(g & (LL - 1));
    const int bh = (int)(g >> 11);
    const int h  = bh & (HH - 1);
    const int b  = bh >> 4;
    const float* arow = ao + g * 32;
    float s = bd[hd];
    #pragma unroll
    for (int c4 = 0; c4 < 8; ++c4) {
        float4 av = *(const float4*)(arow + c4 * 4);
        s += av.x * Ws[hd][c4 * 4 + 0] + av.y * Ws[hd][c4 * 4 + 1]
           + av.z * Ws[hd][c4 * 4 + 2] + av.w * Ws[hd][c4 * 4 + 3];
    }
    out[(size_t)(b * LL + l) * DD + h * HDIM + hd] = (__bf16)s;
}

extern "C" void kernel_launch(void* const* d_in, const int* in_sizes, int n_in,
                              void* d_out, int out_size, void* d_ws, size_t ws_size,
                              hipStream_t stream)
{
    const float* x   = (const float*)d_in[0];
    const float* fc  = (const float*)d_in[1];
    const float* Wq  = (const float*)d_in[2];
    const float* bq  = (const float*)d_in[3];
    const float* Wk  = (const float*)d_in[4];
    const float* bk  = (const float*)d_in[5];
    const float* Wv  = (const float*)d_in[6];
    const float* bv  = (const float*)d_in[7];
    const float* Wqc = (const float*)d_in[8];
    const float* bqc = (const float*)d_in[9];
    const float* Wkc = (const float*)d_in[10];
    const float* bkc = (const float*)d_in[11];
    const float* Wvc = (const float*)d_in[12];
    const float* bvc = (const float*)d_in[13];
    const float* Wd  = (const float*)d_in[14];
    const float* bd  = (const float*)d_in[15];
    const float* Wo  = (const float*)d_in[16];
    const float* bo  = (const float*)d_in[17];
    float* out = (float*)d_out;

    // workspace layout (151 MB total)
    char* w = (char*)d_ws;
    __bf16* xb  = (__bf16*)w; w += (size_t)4096 * 2048 * 2;   // [0,16M)   dead after GEMMs
    __bf16* Wqb = (__bf16*)w; w += (size_t)2048 * 2048 * 2;   // [16M,24M) dead after GEMM q
    __bf16* Wkb = (__bf16*)w; w += (size_t)2048 * 2048 * 2;   // [24M,32M)
    __bf16* Wvb = (__bf16*)w; w += (size_t)2048 * 2048 * 2;   // [32M,40M)
    __bf16* Wob = (__bf16*)w; w += (size_t)2048 * 2048 * 2;   // [40M,48M) live till end
    __bf16* qb  = (__bf16*)w; w += (size_t)4096 * 2048 * 2;
    __bf16* kb  = (__bf16*)w; w += (size_t)4096 * 2048 * 2;
    __bf16* vb  = (__bf16*)w; w += (size_t)4096 * 2048 * 2;
    __bf16* qcbf = (__bf16*)w; w += (size_t)65536 * 32 * 4;  // bf16 in f32-sized slot
    __bf16* kcbf = (__bf16*)w; w += (size_t)65536 * 32 * 4;
    __bf16* vtbf = (__bf16*)w; w += (size_t)65536 * 32 * 4;
    float*  aob  = (float*)w;  w += (size_t)65536 * 32 * 4;
    __bf16* adb = (__bf16*)w;  w += (size_t)4096 * 2048 * 2;

    // attention partials alias xb..Wvb (dead by then): 33.5M + 1M + 1M < 40M
    float* po = (float*)d_ws;
    float* pm = (float*)((char*)d_ws + 33554432);
    float* pl = (float*)((char*)d_ws + 34603008);

    if (ws_size < (size_t)150994944) return;  // fail loudly (zero output) rather than corrupt

    cvt_f32_bf16<<<8192, 256, 0, stream>>>(x,  xb,  2097152);
    cvt_f32_bf16<<<4096, 256, 0, stream>>>(Wq, Wqb, 1048576);
    cvt_f32_bf16<<<4096, 256, 0, stream>>>(Wk, Wkb, 1048576);
    cvt_f32_bf16<<<4096, 256, 0, stream>>>(Wv, Wvb, 1048576);
    cvt_f32_bf16<<<4096, 256, 0, stream>>>(Wo, Wob, 1048576);

    dim3 ggrid(16, 32);
    gemm_bt<true><<<ggrid, 256, 0, stream>>>(xb, Wqb, bq, qb, 4096, 2048, 2048);
    gemm_bt<true><<<ggrid, 256, 0, stream>>>(xb, Wkb, bk, kb, 4096, 2048, 2048);
    gemm_bt<true><<<ggrid, 256, 0, stream>>>(xb, Wvb, bv, vb, 4096, 2048, 2048);

    rope_k<<<dim3(4096, 2), 256, 0, stream>>>(qb, kb, fc);

    latproj<<<dim3(8192, 3), 256, 0, stream>>>(qb, kb, vb, Wqc, bqc, Wkc, bkc, Wvc, bvc,
                                               qcbf, kcbf, vtbf);

    attn_part<<<5120, 64, 0, stream>>>(qcbf, kcbf, vtbf, pm, pl, po);
    attn_comb<<<256, 256, 0, stream>>>(pm, pl, po, aob);

    wd_k<<<32768, 256, 0, stream>>>(aob, Wd, bd, adb);

    gemm_bt<false><<<ggrid, 256, 0, stream>>>(adb, Wob, bo, out, 4096, 2048, 2048);
}

// Round 5
// 315.880 us; speedup vs baseline: 4.0364x; 1.3578x over previous
//
#include <hip/hip_runtime.h>

typedef __attribute__((ext_vector_type(8))) __bf16 bf16x8;
typedef __attribute__((ext_vector_type(4))) __bf16 bf16x4;
typedef __attribute__((ext_vector_type(4))) float f32x4;
typedef __attribute__((ext_vector_type(16))) float f32x16;

#define LL 2048
#define DD 2048
#define HH 16
#define HDIM 128

// ---------------- fp32 -> bf16 conversion ----------------
__global__ void cvt_f32_bf16(const float* __restrict__ src, __bf16* __restrict__ dst, int n4)
{
    int i = blockIdx.x * blockDim.x + threadIdx.x;
    if (i < n4) {
        float4 v = *(const float4*)(src + (size_t)i * 4);
        bf16x4 o = { (__bf16)v.x, (__bf16)v.y, (__bf16)v.z, (__bf16)v.w };
        *(bf16x4*)(dst + (size_t)i * 4) = o;
    }
}

// small-weights conversion: 4 arrays of 4096 floats each
__global__ void cvt_w4(const float* __restrict__ a0, const float* __restrict__ a1,
                       const float* __restrict__ a2, const float* __restrict__ a3,
                       __bf16* __restrict__ o0, __bf16* __restrict__ o1,
                       __bf16* __restrict__ o2, __bf16* __restrict__ o3)
{
    const float* s[4] = { a0, a1, a2, a3 };
    __bf16* d[4] = { o0, o1, o2, o3 };
    const int w = blockIdx.y;
    const int i = blockIdx.x * 256 + threadIdx.x;   // 1024 float4 per array
    float4 v = *(const float4*)(s[w] + (size_t)i * 4);
    bf16x4 o = { (__bf16)v.x, (__bf16)v.y, (__bf16)v.z, (__bf16)v.w };
    *(bf16x4*)(d[w] + (size_t)i * 4) = o;
}

// ---------------- global -> LDS async 16B ----------------
typedef unsigned int u32;
typedef const __attribute__((address_space(1))) u32* gp_t;
typedef __attribute__((address_space(3))) u32* lp_t;
__device__ __forceinline__ void gload16(const __bf16* g, __bf16* l)
{
    __builtin_amdgcn_global_load_lds((gp_t)(const void*)g, (lp_t)(void*)l, 16, 0, 0);
}

// ---------------- bf16 GEMM (m97 structure): C = A(MxK) @ W(NxK)^T + bias ----
template<bool OUT_BF16>
__global__ __launch_bounds__(256)
void gemm_bt(const __bf16* __restrict__ A, const __bf16* __restrict__ W,
             const float* __restrict__ bias, void* __restrict__ Cout,
             int M, int N, int K)
{
    __shared__ __bf16 As[128][64];
    __shared__ __bf16 Bs[128][64];
    const int tid  = threadIdx.x;
    const int m0   = blockIdx.y * 128;
    const int n0   = blockIdx.x * 128;
    const int wave = tid >> 6;
    const int lane = tid & 63;
    const int wr   = (wave >> 1) * 64;
    const int wc   = (wave & 1) * 64;
    const int lr   = lane & 15;
    const int lk   = (lane >> 4) * 8;
    const int srow = wave * 32 + (lane >> 3);
    const int scol = (lane & 7) * 8;

    f32x4 acc[4][4] = {};
    const __bf16* Aw = A + (size_t)(m0 + srow) * K + scol;
    const __bf16* Ww = W + (size_t)(n0 + srow) * K + scol;
    __bf16* lA = &As[wave * 32][0];    // wave-uniform base; HW adds lane*16B
    __bf16* lB = &Bs[wave * 32][0];

    for (int k0 = 0; k0 < K; k0 += 64) {
        #pragma unroll
        for (int j = 0; j < 4; ++j) {
            gload16(Aw + (size_t)(j * 8) * K + k0, lA + j * 512);
            gload16(Ww + (size_t)(j * 8) * K + k0, lB + j * 512);
        }
        __syncthreads();
        #pragma unroll
        for (int ks = 0; ks < 2; ++ks) {
            bf16x8 af[4], bfr[4];
            #pragma unroll
            for (int m = 0; m < 4; ++m)
                af[m] = *(const bf16x8*)(&As[wr + m * 16 + lr][ks * 32 + lk]);
            #pragma unroll
            for (int n = 0; n < 4; ++n)
                bfr[n] = *(const bf16x8*)(&Bs[wc + n * 16 + lr][ks * 32 + lk]);
            #pragma unroll
            for (int m = 0; m < 4; ++m)
                #pragma unroll
                for (int n = 0; n < 4; ++n)
                    acc[m][n] = __builtin_amdgcn_mfma_f32_16x16x32_bf16(af[m], bfr[n], acc[m][n], 0, 0, 0);
        }
        __syncthreads();
    }

    const int orow = (lane >> 4) * 4;
    #pragma unroll
    for (int n = 0; n < 4; ++n) {
        const int col = n0 + wc + n * 16 + lr;
        const float bv = bias[col];
        #pragma unroll
        for (int m = 0; m < 4; ++m) {
            #pragma unroll
            for (int r = 0; r < 4; ++r) {
                const int row = m0 + wr + m * 16 + orow + r;
                const float v = acc[m][n][r] + bv;
                if (OUT_BF16) ((__bf16*)Cout)[(size_t)row * N + col] = (__bf16)v;
                else          ((float*)Cout)[(size_t)row * N + col]  = v;
            }
        }
    }
}

// ---------------- RoPE (in-place on bf16 q/k, layout (B,L,H*HD)) ----------------
__global__ void rope_k(__bf16* __restrict__ q, __bf16* __restrict__ k, const float* __restrict__ fc)
{
    __bf16* t = blockIdx.y ? k : q;
    const size_t e0 = ((size_t)blockIdx.x * blockDim.x + threadIdx.x) * 8;  // 4 pairs
    const int row = (int)(e0 >> 11);          // b*L + l
    const int l   = row & (LL - 1);
    const int j0  = (int)((e0 & (HDIM - 1)) >> 1);  // pair index within head
    bf16x8 v = *(bf16x8*)(t + e0);
    float4 c01 = *(const float4*)(fc + ((size_t)l * 64 + j0) * 2);
    float4 c23 = *(const float4*)(fc + ((size_t)l * 64 + j0 + 2) * 2);
    float cr[4] = { c01.x, c01.z, c23.x, c23.z };
    float ci[4] = { c01.y, c01.w, c23.y, c23.w };
    #pragma unroll
    for (int p = 0; p < 4; ++p) {
        float a = (float)v[2 * p], b = (float)v[2 * p + 1];
        v[2 * p]     = (__bf16)(a * cr[p] - b * ci[p]);
        v[2 * p + 1] = (__bf16)(a * ci[p] + b * cr[p]);
    }
    *(bf16x8*)(t + e0) = v;
}

// ---------------- latent projections via MFMA: 65536x32x128 GEMM x3 ----------
// One wave: 32 rows x 32 latents, K=128 -> 8 mfma_32x32x16.
// A: row=lane&31, k=hi*8+j (HW-verified mapping). B = W^T via W rows.
__global__ __launch_bounds__(256)
void latproj_mfma(const __bf16* __restrict__ qb, const __bf16* __restrict__ kb,
                  const __bf16* __restrict__ vb,
                  const __bf16* __restrict__ Wqcb, const __bf16* __restrict__ Wkcb,
                  const __bf16* __restrict__ Wvcb,
                  const float* __restrict__ bq, const float* __restrict__ bk,
                  const float* __restrict__ bv,
                  __bf16* __restrict__ qc, __bf16* __restrict__ kc, __bf16* __restrict__ vt)
{
    const int which = blockIdx.y;
    const __bf16* in = which == 0 ? qb : which == 1 ? kb : vb;
    const __bf16* Wb = which == 0 ? Wqcb : which == 1 ? Wkcb : Wvcb;
    const float*  bs = which == 0 ? bq : which == 1 ? bk : bv;

    const int wave = threadIdx.x >> 6;
    const int lane = threadIdx.x & 63;
    const int o    = lane & 31;
    const int hi   = lane >> 5;
    const int g0   = (blockIdx.x * 4 + wave) * 32;   // row block (g = bh*2048 + l)

    // B fragments: col=o needs W[o][k] slices
    bf16x8 wf[8];
    #pragma unroll
    for (int ks = 0; ks < 8; ++ks)
        wf[ks] = *(const bf16x8*)(Wb + o * 128 + ks * 16 + hi * 8);

    // A row for this lane
    const int g = g0 + o;
    const int b = g >> 15, h = (g >> 11) & 15, l = g & (LL - 1);
    const __bf16* arow = in + ((size_t)(b * LL + l)) * DD + h * HDIM;

    f32x16 C = {};
    #pragma unroll
    for (int ks = 0; ks < 8; ++ks) {
        bf16x8 af = *(const bf16x8*)(arow + ks * 16 + hi * 8);
        C = __builtin_amdgcn_mfma_f32_32x32x16_bf16(af, wf[ks], C, 0, 0, 0);
    }

    const float bias = bs[o];
    const float QSCALE = 0.17677669529663689f * 1.44269504088896340f;
    if (which == 2) {
        // vt[(bh*32 + o)*LL + l], rows (r&3)+8*(r>>2)+4*hi consecutive in groups of 4
        const int bh = g0 >> 11, l0 = g0 & (LL - 1);
        __bf16* vrow = vt + ((size_t)bh * 32 + o) * LL + l0;
        #pragma unroll
        for (int gq = 0; gq < 4; ++gq) {
            bf16x4 pk = { (__bf16)(C[gq * 4 + 0] + bias), (__bf16)(C[gq * 4 + 1] + bias),
                          (__bf16)(C[gq * 4 + 2] + bias), (__bf16)(C[gq * 4 + 3] + bias) };
            *(bf16x4*)(vrow + gq * 8 + hi * 4) = pk;
        }
    } else {
        __bf16* outp = (which == 0 ? qc : kc);
        #pragma unroll
        for (int r = 0; r < 16; ++r) {
            const int ro = (r & 3) + 8 * (r >> 2) + 4 * hi;
            float v = C[r] + bias;
            if (which == 0) v *= QSCALE;
            outp[(size_t)(g0 + ro) * 32 + o] = (__bf16)v;
        }
    }
}

// ---------------- helpers for MFMA attention ----------------
__device__ __forceinline__ unsigned pkbf2(float a, float b)
{
    union { __bf16 h[2]; unsigned u; } x;
    x.h[0] = (__bf16)a; x.h[1] = (__bf16)b;
    return x.u;
}

#if __has_builtin(__builtin_amdgcn_permlane32_swap)
typedef unsigned int uint2v __attribute__((ext_vector_type(2)));
__device__ __forceinline__ void plswap(unsigned a, unsigned b, unsigned& w_lo, unsigned& w_hi, int)
{
    uint2v r = __builtin_amdgcn_permlane32_swap(a, b, false, false);
    w_lo = r[0]; w_hi = r[1];
}
#else
__device__ __forceinline__ void plswap(unsigned a, unsigned b, unsigned& w_lo, unsigned& w_hi, int hi)
{
    unsigned ax = (unsigned)__shfl_xor((int)a, 32);
    unsigned bx = (unsigned)__shfl_xor((int)b, 32);
    w_lo = hi ? bx : a;
    w_hi = hi ? b  : ax;
}
#endif

// ---------------- split-K causal flash attention via MFMA ----------------
__global__ __launch_bounds__(64)
void attn_part(const __bf16* __restrict__ qc, const __bf16* __restrict__ kc,
               const __bf16* __restrict__ vt,
               float* __restrict__ pm, float* __restrict__ pl, float* __restrict__ po)
{
    const int id  = blockIdx.x;
    const int bhl = id & 7;
    const int c   = id >> 3;
    const int bhh = c / 160;
    const int lin = c - bhh * 160;
    int s, ci;
    if (lin < 16)      { s = lin; ci = 0; }
    else if (lin < 48) { int q = lin - 16; s = 16 + (q >> 1); ci = q & 1; }
    else if (lin < 96) { int q = lin - 48; int d = q / 3; s = 32 + d; ci = q - d * 3; }
    else               { int q = lin - 96; s = 48 + (q >> 2); ci = q & 3; }
    const int bh = bhh * 8 + bhl;

    const int lane = threadIdx.x;
    const int qcol = lane & 31;
    const int hi   = lane >> 5;

    const __bf16* qbase = qc + ((size_t)bh * LL + (size_t)s * 32) * 32;
    const __bf16* kbase = kc + (size_t)bh * LL * 32;
    const __bf16* vbase = vt + (size_t)bh * 32 * LL;

    const bf16x8 qf0 = *(const bf16x8*)(qbase + qcol * 32 + hi * 8);
    const bf16x8 qf1 = *(const bf16x8*)(qbase + qcol * 32 + 16 + hi * 8);

    float m = -1e30f, lsum = 0.f;
    f32x16 O = {};

    const int t0 = ci * 16;
    const int t1 = min(s, t0 + 15);

    const __bf16* krow = kbase + (size_t)(t0 * 32 + qcol) * 32 + hi * 8;
    const __bf16* vrow = vbase + (size_t)qcol * LL + t0 * 32 + hi * 8;
    bf16x8 kc0 = *(const bf16x8*)(krow);
    bf16x8 kc1 = *(const bf16x8*)(krow + 16);
    bf16x8 vc0 = *(const bf16x8*)(vrow);
    bf16x8 vc1 = *(const bf16x8*)(vrow + 16);

    for (int t = t0; t <= t1; ++t) {
        const int tn = (t < t1) ? t + 1 : t;
        const __bf16* krn = kbase + (size_t)(tn * 32 + qcol) * 32 + hi * 8;
        const __bf16* vrn = vbase + (size_t)qcol * LL + tn * 32 + hi * 8;
        bf16x8 kn0 = *(const bf16x8*)(krn);
        bf16x8 kn1 = *(const bf16x8*)(krn + 16);
        bf16x8 vn0 = *(const bf16x8*)(vrn);
        bf16x8 vn1 = *(const bf16x8*)(vrn + 16);

        f32x16 S = {};
        S = __builtin_amdgcn_mfma_f32_32x32x16_bf16(kc0, qf0, S, 0, 0, 0);
        S = __builtin_amdgcn_mfma_f32_32x32x16_bf16(kc1, qf1, S, 0, 0, 0);

        if (t == s) {
            #pragma unroll
            for (int r = 0; r < 16; ++r) {
                const int kl = (r & 3) + 8 * (r >> 2) + 4 * hi;
                if (kl > qcol) S[r] = -1e30f;
            }
        }
        float tm = S[0];
        #pragma unroll
        for (int r = 1; r < 16; ++r) tm = fmaxf(tm, S[r]);
        tm = fmaxf(tm, __shfl_xor(tm, 32));
        const float mn = fmaxf(m, tm);
        const float fr = exp2f(m - mn);
        m = mn;
        float p[16]; float ls = 0.f;
        #pragma unroll
        for (int r = 0; r < 16; ++r) { p[r] = exp2f(S[r] - m); ls += p[r]; }
        lsum = lsum * fr + ls;
        #pragma unroll
        for (int r = 0; r < 16; ++r) O[r] *= fr;

        unsigned w[8];
        #pragma unroll
        for (int i = 0; i < 8; ++i) w[i] = pkbf2(p[2 * i], p[2 * i + 1]);
        union PF { unsigned u[4]; bf16x8 v; } pf1, pf2;
        plswap(w[0], w[2], pf1.u[0], pf1.u[2], hi);
        plswap(w[1], w[3], pf1.u[1], pf1.u[3], hi);
        plswap(w[4], w[6], pf2.u[0], pf2.u[2], hi);
        plswap(w[5], w[7], pf2.u[1], pf2.u[3], hi);

        O = __builtin_amdgcn_mfma_f32_32x32x16_bf16(vc0, pf1.v, O, 0, 0, 0);
        O = __builtin_amdgcn_mfma_f32_32x32x16_bf16(vc1, pf2.v, O, 0, 0, 0);

        kc0 = kn0; kc1 = kn1; vc0 = vn0; vc1 = vn1;
    }

    const float L = lsum + __shfl_xor(lsum, 32);
    const size_t g = (size_t)bh * LL + (size_t)s * 32 + qcol;
    const size_t slot = g * 4 + ci;
    if (hi == 0) { pm[slot] = m; pl[slot] = L; }
    float* pp = po + slot * 32;
    #pragma unroll
    for (int g4 = 0; g4 < 4; ++g4) {
        float4 v = { O[g4 * 4 + 0], O[g4 * 4 + 1], O[g4 * 4 + 2], O[g4 * 4 + 3] };
        *(float4*)(pp + g4 * 8 + 4 * hi) = v;
    }
}

// ---------------- split-K attention combine -> bf16 ao ----------------
__global__ __launch_bounds__(256)
void attn_comb(const float* __restrict__ pm, const float* __restrict__ pl,
               const float* __restrict__ po, __bf16* __restrict__ ao)
{
    const int g = blockIdx.x * 256 + threadIdx.x;   // 0..65535
    const int i = g & (LL - 1);
    const int nch = (i >> 9) + 1;
    float m = -1e30f;
    for (int c = 0; c < nch; ++c) m = fmaxf(m, pm[(size_t)g * 4 + c]);
    float L = 0.f;
    float o[32] = {};
    for (int c = 0; c < nch; ++c) {
        const float w = exp2f(pm[(size_t)g * 4 + c] - m);
        L += w * pl[(size_t)g * 4 + c];
        const float* pp = po + ((size_t)g * 4 + c) * 32;
        #pragma unroll
        for (int d4 = 0; d4 < 8; ++d4) {
            float4 v = *(const float4*)(pp + d4 * 4);
            o[d4*4+0] += w * v.x; o[d4*4+1] += w * v.y;
            o[d4*4+2] += w * v.z; o[d4*4+3] += w * v.w;
        }
    }
    const float inv = 1.f / L;
    #pragma unroll
    for (int d8 = 0; d8 < 4; ++d8) {
        bf16x8 v;
        #pragma unroll
        for (int j = 0; j < 8; ++j) v[j] = (__bf16)(o[d8 * 8 + j] * inv);
        *(bf16x8*)(ao + (size_t)g * 32 + d8 * 8) = v;
    }
}

// ---------------- decode 32 -> 128 via MFMA: 65536x128x32 GEMM ----------------
// One wave: 32 rows x 128 cols = 4 col-blocks x (2 mfma K=16).
__global__ __launch_bounds__(256)
void wd_mfma(const __bf16* __restrict__ ao, const __bf16* __restrict__ Wdb,
             const float* __restrict__ bd, __bf16* __restrict__ out)
{
    const int wave = threadIdx.x >> 6;
    const int lane = threadIdx.x & 63;
    const int o    = lane & 31;
    const int hi   = lane >> 5;
    const int g0   = (blockIdx.x * 4 + wave) * 32;

    bf16x8 wf[4][2];
    #pragma unroll
    for (int cb = 0; cb < 4; ++cb) {
        const __bf16* wrow = Wdb + (size_t)(cb * 32 + o) * 32 + hi * 8;
        wf[cb][0] = *(const bf16x8*)(wrow);
        wf[cb][1] = *(const bf16x8*)(wrow + 16);
    }

    const __bf16* arow = ao + (size_t)(g0 + o) * 32 + hi * 8;
    const bf16x8 a0 = *(const bf16x8*)(arow);
    const bf16x8 a1 = *(const bf16x8*)(arow + 16);

    f32x16 C[4] = {};
    #pragma unroll
    for (int cb = 0; cb < 4; ++cb) {
        C[cb] = __builtin_amdgcn_mfma_f32_32x32x16_bf16(a0, wf[cb][0], C[cb], 0, 0, 0);
        C[cb] = __builtin_amdgcn_mfma_f32_32x32x16_bf16(a1, wf[cb][1], C[cb], 0, 0, 0);
    }

    const int b = g0 >> 15, h = (g0 >> 11) & 15, l0 = g0 & (LL - 1);
    #pragma unroll
    for (int cb = 0; cb < 4; ++cb) {
        const float bias = bd[cb * 32 + o];
        #pragma unroll
        for (int r = 0; r < 16; ++r) {
            const int ro = (r & 3) + 8 * (r >> 2) + 4 * hi;
            out[(size_t)(b * LL + l0 + ro) * DD + h * HDIM + cb * 32 + o] =
                (__bf16)(C[cb][r] + bias);
        }
    }
}

extern "C" void kernel_launch(void* const* d_in, const int* in_sizes, int n_in,
                              void* d_out, int out_size, void* d_ws, size_t ws_size,
                              hipStream_t stream)
{
    const float* x   = (const float*)d_in[0];
    const float* fc  = (const float*)d_in[1];
    const float* Wq  = (const float*)d_in[2];
    const float* bq  = (const float*)d_in[3];
    const float* Wk  = (const float*)d_in[4];
    const float* bk  = (const float*)d_in[5];
    const float* Wv  = (const float*)d_in[6];
    const float* bv  = (const float*)d_in[7];
    const float* Wqc = (const float*)d_in[8];
    const float* bqc = (const float*)d_in[9];
    const float* Wkc = (const float*)d_in[10];
    const float* bkc = (const float*)d_in[11];
    const float* Wvc = (const float*)d_in[12];
    const float* bvc = (const float*)d_in[13];
    const float* Wd  = (const float*)d_in[14];
    const float* bd  = (const float*)d_in[15];
    const float* Wo  = (const float*)d_in[16];
    const float* bo  = (const float*)d_in[17];
    float* out = (float*)d_out;

    // workspace layout (144 MiB total)
    char* w = (char*)d_ws;
    __bf16* xb  = (__bf16*)w; w += (size_t)4096 * 2048 * 2;   // [0,16M)   dead after GEMMs
    __bf16* Wqb = (__bf16*)w; w += (size_t)2048 * 2048 * 2;
    __bf16* Wkb = (__bf16*)w; w += (size_t)2048 * 2048 * 2;
    __bf16* Wvb = (__bf16*)w; w += (size_t)2048 * 2048 * 2;
    __bf16* Wob = (__bf16*)w; w += (size_t)2048 * 2048 * 2;   // live till end
    __bf16* qb  = (__bf16*)w; w += (size_t)4096 * 2048 * 2;
    __bf16* kb  = (__bf16*)w; w += (size_t)4096 * 2048 * 2;
    __bf16* vb  = (__bf16*)w; w += (size_t)4096 * 2048 * 2;
    __bf16* qcbf = (__bf16*)w; w += (size_t)65536 * 32 * 4;  // bf16 in f32-sized slot (half free)
    __bf16* kcbf = (__bf16*)w; w += (size_t)65536 * 32 * 4;
    __bf16* vtbf = (__bf16*)w; w += (size_t)65536 * 32 * 4;
    __bf16* aobf = (__bf16*)w; w += (size_t)65536 * 32 * 4;  // bf16 ao (half slot free)
    __bf16* adb = (__bf16*)w;  w += (size_t)4096 * 2048 * 2;

    // small bf16 weights in the unused upper half of the qcbf slot (4 MiB free)
    __bf16* Wqcb = (__bf16*)((char*)qcbf + 4194304);
    __bf16* Wkcb = Wqcb + 4096;
    __bf16* Wvcb = Wkcb + 4096;
    __bf16* Wdb  = Wvcb + 4096;

    // attention partials alias xb..Wvb (dead by then): 33.5M + 1M + 1M < 40M
    float* po = (float*)d_ws;
    float* pm = (float*)((char*)d_ws + 33554432);
    float* pl = (float*)((char*)d_ws + 34603008);

    if (ws_size < (size_t)150994944) return;  // fail loudly (zero output) rather than corrupt

    cvt_f32_bf16<<<8192, 256, 0, stream>>>(x,  xb,  2097152);
    cvt_f32_bf16<<<4096, 256, 0, stream>>>(Wq, Wqb, 1048576);
    cvt_f32_bf16<<<4096, 256, 0, stream>>>(Wk, Wkb, 1048576);
    cvt_f32_bf16<<<4096, 256, 0, stream>>>(Wv, Wvb, 1048576);
    cvt_f32_bf16<<<4096, 256, 0, stream>>>(Wo, Wob, 1048576);
    cvt_w4<<<dim3(4, 4), 256, 0, stream>>>(Wqc, Wkc, Wvc, Wd, Wqcb, Wkcb, Wvcb, Wdb);

    dim3 ggrid(16, 32);
    gemm_bt<true><<<ggrid, 256, 0, stream>>>(xb, Wqb, bq, qb, 4096, 2048, 2048);
    gemm_bt<true><<<ggrid, 256, 0, stream>>>(xb, Wkb, bk, kb, 4096, 2048, 2048);
    gemm_bt<true><<<ggrid, 256, 0, stream>>>(xb, Wvb, bv, vb, 4096, 2048, 2048);

    rope_k<<<dim3(4096, 2), 256, 0, stream>>>(qb, kb, fc);

    latproj_mfma<<<dim3(512, 3), 256, 0, stream>>>(qb, kb, vb, Wqcb, Wkcb, Wvcb,
                                                   bqc, bkc, bvc, qcbf, kcbf, vtbf);

    attn_part<<<5120, 64, 0, stream>>>(qcbf, kcbf, vtbf, pm, pl, po);
    attn_comb<<<256, 256, 0, stream>>>(pm, pl, po, aobf);

    wd_mfma<<<512, 256, 0, stream>>>(aobf, Wdb, bd, adb);

    gemm_bt<false><<<ggrid, 256, 0, stream>>>(adb, Wob, bo, out, 4096, 2048, 2048);
}